// Round 18
// baseline (5394.763 us; speedup 1.0000x reference)
//
#include <hip/hip_runtime.h>
#include <math.h>

#define BB 64
#define SS 48
#define EE 256
#define HH 512
#define VV 30000
#define G3 1536   // 3*H
#define NPB 235   // ceil(VV/128) proj blocks
#define TAU 0.04f

typedef __attribute__((ext_vector_type(8))) short s8v;
typedef __attribute__((ext_vector_type(4))) short s4v;
typedef __attribute__((ext_vector_type(4))) float f4v;

__device__ __forceinline__ float sigmoidf_(float x) { return 1.f / (1.f + expf(-x)); }

__device__ __forceinline__ short f2bf(float x) {
    union { float f; unsigned u; } v; v.f = x;
    unsigned r = v.u + 0x7fffu + ((v.u >> 16) & 1u);
    return (short)(r >> 16);
}

// ---------- split fp32 -> bf16 hi only (proven) ----------
__global__ __launch_bounds__(256) void split_hi_kernel(
    const float* __restrict__ src, long n4, short* __restrict__ hi)
{
    for (long i = (long)blockIdx.x * 256 + threadIdx.x; i < n4;
         i += (long)gridDim.x * 256) {
        const float4 x = *(const float4*)&src[i * 4];
        s4v h;
        h[0] = f2bf(x.x); h[1] = f2bf(x.y); h[2] = f2bf(x.z); h[3] = f2bf(x.w);
        *(s4v*)&hi[i * 4] = h;
    }
}

// ---------- encoder gi for ALL steps (proven) ----------
__global__ __launch_bounds__(256) void enc_gi_all_kernel(
    const int* __restrict__ input,
    const float* __restrict__ embed,
    const float* __restrict__ wih,
    float* __restrict__ gi_all)           // [S][G3][B]
{
    __shared__ float Wt[64][68];
    __shared__ float Xt[64][68];
    const int t  = threadIdx.x;
    const int tx = t & 15, ty = t >> 4;
    const int j0 = blockIdx.x * 64;
    const int s  = blockIdx.y;
    const int bb = t & 63, kq = t >> 6;
    const int wkk = (t & 15) * 4, wjj = t >> 4;

    const long xrow = (long)input[bb * SS + s] * EE;
    float* gi = gi_all + (long)s * G3 * BB;

    float acc[4][4];
    #pragma unroll
    for (int i = 0; i < 4; i++)
        #pragma unroll
        for (int j = 0; j < 4; j++) acc[i][j] = 0.f;

    for (int kb = 0; kb < EE; kb += 64) {
        #pragma unroll
        for (int r = 0; r < 4; r++) {
            int row = j0 + wjj + r * 16;
            const float4 w = *(const float4*)&wih[row * EE + kb + wkk];
            Wt[wkk + 0][wjj + r * 16] = w.x;
            Wt[wkk + 1][wjj + r * 16] = w.y;
            Wt[wkk + 2][wjj + r * 16] = w.z;
            Wt[wkk + 3][wjj + r * 16] = w.w;
        }
        {
            const float* src = embed + xrow + kb + kq * 16;
            #pragma unroll
            for (int q = 0; q < 4; q++) {
                const float4 x = *(const float4*)&src[q * 4];
                Xt[kq * 16 + q * 4 + 0][bb] = x.x;
                Xt[kq * 16 + q * 4 + 1][bb] = x.y;
                Xt[kq * 16 + q * 4 + 2][bb] = x.z;
                Xt[kq * 16 + q * 4 + 3][bb] = x.w;
            }
        }
        __syncthreads();
        #pragma unroll 8
        for (int k = 0; k < 64; k++) {
            const float4 a = *(const float4*)&Wt[k][ty * 4];
            const float4 x = *(const float4*)&Xt[k][tx * 4];
            acc[0][0] += a.x * x.x; acc[0][1] += a.x * x.y; acc[0][2] += a.x * x.z; acc[0][3] += a.x * x.w;
            acc[1][0] += a.y * x.x; acc[1][1] += a.y * x.y; acc[1][2] += a.y * x.z; acc[1][3] += a.y * x.w;
            acc[2][0] += a.z * x.x; acc[2][1] += a.z * x.y; acc[2][2] += a.z * x.z; acc[2][3] += a.z * x.w;
            acc[3][0] += a.w * x.x; acc[3][1] += a.w * x.y; acc[3][2] += a.w * x.z; acc[3][3] += a.w * x.w;
        }
        __syncthreads();
    }
    #pragma unroll
    for (int i = 0; i < 4; i++) {
        float4 o; o.x = acc[i][0]; o.y = acc[i][1]; o.z = acc[i][2]; o.w = acc[i][3];
        *(float4*)&gi[(j0 + ty * 4 + i) * BB + tx * 4] = o;
    }
}

// ---------- fused encoder step: 256 blocks x 2 hidden, 128 threads (bit-identical repartition) ----------
__global__ __launch_bounds__(128) void enc_step_kernel(
    const float* __restrict__ gi_s,
    const float* __restrict__ whh,
    const float* __restrict__ bih, const float* __restrict__ bhh,
    const float* __restrict__ hprev, int s,
    float* __restrict__ enc_states)
{
    __shared__ __attribute__((aligned(16))) float Wt[64][7];   // [k][g*2+r]
    __shared__ __attribute__((aligned(16))) float Xt[64][68];
    const int t = threadIdx.x;
    const int tx = t & 63, ty = t >> 6;          // b, hidden offset (0..1)
    const int bb = t & 63, kq = t >> 6;          // X staging (kq 0..1)
    const int h0 = blockIdx.x * 2;

    float accr = 0.f, accz = 0.f, acchn = 0.f;

    if (hprev) {
        const float* xr = hprev + (long)bb * (SS * HH);
        for (int kb = 0; kb < HH; kb += 64) {
            // W: 6 rows (3 gates x 2 hidden) x 64 k, strided over 128 threads (float2 units)
            for (int idx = t; idx < 6 * 32; idx += 128) {
                int row = idx >> 5, c2 = (idx & 31) * 2;
                int g = row >> 1, r = row & 1;
                const float2 w = *(const float2*)&whh[(long)(g * HH + h0 + r) * HH + kb + c2];
                Wt[c2 + 0][g * 2 + r] = w.x;
                Wt[c2 + 1][g * 2 + r] = w.y;
            }
            {
                const float* src = xr + kb + kq * 32;
                #pragma unroll
                for (int q = 0; q < 8; q++) {
                    const float4 x = *(const float4*)&src[q * 4];
                    Xt[kq * 32 + q * 4 + 0][bb] = x.x;
                    Xt[kq * 32 + q * 4 + 1][bb] = x.y;
                    Xt[kq * 32 + q * 4 + 2][bb] = x.z;
                    Xt[kq * 32 + q * 4 + 3][bb] = x.w;
                }
            }
            __syncthreads();
            #pragma unroll 8
            for (int k = 0; k < 64; k++) {
                float x = Xt[k][tx];
                accr  += Wt[k][ty] * x;
                accz  += Wt[k][2 + ty] * x;
                acchn += Wt[k][4 + ty] * x;
            }
            __syncthreads();
        }
    }

    const int j = h0 + ty;
    const int b = tx;
    float r = sigmoidf_(gi_s[(long)j * BB + b] + accr + bih[j] + bhh[j]);
    float z = sigmoidf_(gi_s[(long)(HH + j) * BB + b] + accz + bih[HH + j] + bhh[HH + j]);
    float n = tanhf(gi_s[(long)(2 * HH + j) * BB + b] + bih[2 * HH + j] + r * (acchn + bhh[2 * HH + j]));
    float hp = hprev ? hprev[(long)b * (SS * HH) + j] : 0.f;
    enc_states[((long)b * SS + s) * HH + j] = (1.f - z) * n + z * hp;
}

// ---------- fused decoder step: 256 blocks x 2 hidden, 128 threads (bit-identical repartition) ----------
__global__ __launch_bounds__(128) void dec_step_kernel(
    const int* __restrict__ tok, int s,
    const float* __restrict__ embed,
    const float* __restrict__ wih, const float* __restrict__ whh,
    const float* __restrict__ bih, const float* __restrict__ bhh,
    const float* __restrict__ hprev, long hstride,
    float* __restrict__ hbuf)                       // [B][H]
{
    __shared__ __attribute__((aligned(16))) float Wt[64][7];
    __shared__ __attribute__((aligned(16))) float Xt[64][68];
    const int t = threadIdx.x;
    const int tx = t & 63, ty = t >> 6;
    const int bb = t & 63, kq = t >> 6;
    const int h0 = blockIdx.x * 2;

    float accr = 0.f, accz = 0.f, accin = 0.f, acchn = 0.f;

    // ---- phase A: wih (K=EE), X = embed[token] ----
    {
        const int tk = (s == 0) ? 0 : tok[bb];
        const float* xr = embed + (long)tk * EE;
        for (int kb = 0; kb < EE; kb += 64) {
            for (int idx = t; idx < 6 * 32; idx += 128) {
                int row = idx >> 5, c2 = (idx & 31) * 2;
                int g = row >> 1, r = row & 1;
                const float2 w = *(const float2*)&wih[(long)(g * HH + h0 + r) * EE + kb + c2];
                Wt[c2 + 0][g * 2 + r] = w.x;
                Wt[c2 + 1][g * 2 + r] = w.y;
            }
            {
                const float* src = xr + kb + kq * 32;
                #pragma unroll
                for (int q = 0; q < 8; q++) {
                    const float4 x = *(const float4*)&src[q * 4];
                    Xt[kq * 32 + q * 4 + 0][bb] = x.x;
                    Xt[kq * 32 + q * 4 + 1][bb] = x.y;
                    Xt[kq * 32 + q * 4 + 2][bb] = x.z;
                    Xt[kq * 32 + q * 4 + 3][bb] = x.w;
                }
            }
            __syncthreads();
            #pragma unroll 8
            for (int k = 0; k < 64; k++) {
                float x = Xt[k][tx];
                accr  += Wt[k][ty] * x;
                accz  += Wt[k][2 + ty] * x;
                accin += Wt[k][4 + ty] * x;
            }
            __syncthreads();
        }
    }
    // ---- phase B: whh (K=HH), X = hprev ----
    {
        const float* xr = hprev + (long)bb * hstride;
        for (int kb = 0; kb < HH; kb += 64) {
            for (int idx = t; idx < 6 * 32; idx += 128) {
                int row = idx >> 5, c2 = (idx & 31) * 2;
                int g = row >> 1, r = row & 1;
                const float2 w = *(const float2*)&whh[(long)(g * HH + h0 + r) * HH + kb + c2];
                Wt[c2 + 0][g * 2 + r] = w.x;
                Wt[c2 + 1][g * 2 + r] = w.y;
            }
            {
                const float* src = xr + kb + kq * 32;
                #pragma unroll
                for (int q = 0; q < 8; q++) {
                    const float4 x = *(const float4*)&src[q * 4];
                    Xt[kq * 32 + q * 4 + 0][bb] = x.x;
                    Xt[kq * 32 + q * 4 + 1][bb] = x.y;
                    Xt[kq * 32 + q * 4 + 2][bb] = x.z;
                    Xt[kq * 32 + q * 4 + 3][bb] = x.w;
                }
            }
            __syncthreads();
            #pragma unroll 8
            for (int k = 0; k < 64; k++) {
                float x = Xt[k][tx];
                accr  += Wt[k][ty] * x;
                accz  += Wt[k][2 + ty] * x;
                acchn += Wt[k][4 + ty] * x;
            }
            __syncthreads();
        }
    }

    const int j = h0 + ty;
    const int b = tx;
    float r = sigmoidf_(accr + bih[j] + bhh[j]);
    float z = sigmoidf_(accz + bih[HH + j] + bhh[HH + j]);
    float n = tanhf(accin + bih[2 * HH + j] + r * (acchn + bhh[2 * HH + j]));
    float hp = hprev[(long)b * hstride + j];
    hbuf[b * HH + j] = (1.f - z) * n + z * hp;
}

// ---------- decoder attention (proven) ----------
__global__ __launch_bounds__(256) void dec_attn_kernel(
    const float* __restrict__ hbuf,         // [b][H]
    const float* __restrict__ enc_states,   // [b][s][h]
    float* __restrict__ cat_f32,            // [b][2H]
    short* __restrict__ cat_hi)             // [b][2H] bf16
{
    int b = blockIdx.x, t = threadIdx.x;
    __shared__ float hs[HH];
    __shared__ float ctxs[HH];
    __shared__ float sc[SS];

    for (int j = t; j < HH; j += 256) hs[j] = hbuf[b * HH + j];
    __syncthreads();

    int wave = t >> 6, lane = t & 63;
    for (int sp = wave; sp < SS; sp += 4) {
        const float* es = enc_states + ((long)b * SS + sp) * HH;
        float p = 0.f;
        for (int k = lane; k < HH; k += 64) p += es[k] * hs[k];
        for (int o = 32; o; o >>= 1) p += __shfl_down(p, o);
        if (lane == 0) sc[sp] = p;
    }
    __syncthreads();
    if (t == 0) {
        float m = sc[0];
        for (int i = 1; i < SS; i++) m = fmaxf(m, sc[i]);
        float sum = 0.f;
        for (int i = 0; i < SS; i++) { float e = expf(sc[i] - m); sc[i] = e; sum += e; }
        float inv = 1.f / sum;
        for (int i = 0; i < SS; i++) sc[i] *= inv;
    }
    __syncthreads();
    for (int j = t; j < HH; j += 256) {
        float c = 0.f;
        for (int sp = 0; sp < SS; sp++) c += sc[sp] * enc_states[((long)b * SS + sp) * HH + j];
        ctxs[j] = c;
    }
    __syncthreads();
    for (int k = t; k < 2 * HH; k += 256) {
        float val = (k < HH) ? hs[k] : ctxs[k - HH];
        cat_f32[b * 2 * HH + k] = val;
        cat_hi[b * 2 * HH + k] = f2bf(val);
    }
}

// ---------- projection hi-only MFMA + per-block stats + normalize prev (proven fold) ----------
__global__ __launch_bounds__(256) void proj_hi_kernel(
    const short* __restrict__ pw_hi,     // may be null
    const float* __restrict__ pw_f32,
    const short* __restrict__ cat_hi,    // [B][2H]
    const float* __restrict__ pb,
    float* __restrict__ logits,          // [b][V]
    float* __restrict__ pm, float* __restrict__ ps,   // [NPB][64]
    float* __restrict__ prev_logits,     // may be null
    const float* __restrict__ lse_prev)
{
    __shared__ __attribute__((aligned(16))) char smem_raw[64 * 129 * 4];  // 33024 B
    short (*Ah)[72] = (short(*)[72])smem_raw;
    short (*Bh)[72] = (short(*)[72])(smem_raw + 128 * 72 * 2);
    float (*LT)[129] = (float(*)[129])smem_raw;
    __shared__ float sm4[4][64];
    __shared__ float ss4[4][64];

    const int t = threadIdx.x;
    const int lane = t & 63, wave = t >> 6;
    const int v0 = blockIdx.x * 128;

    f4v acc[2][4];
    #pragma unroll
    for (int i = 0; i < 2; i++)
        #pragma unroll
        for (int j = 0; j < 4; j++) acc[i][j] = (f4v){0.f, 0.f, 0.f, 0.f};

    for (int ks = 0; ks < 16; ks++) {
        const int kb = ks * 64;
        if (pw_hi) {
            #pragma unroll
            for (int p = 0; p < 4; p++) {
                int idx = p * 256 + t;
                int r = idx >> 3, c8 = (idx & 7) * 8;
                long vrow = v0 + r; if (vrow >= VV) vrow = VV - 1;
                *(s8v*)&Ah[r][c8] = *(const s8v*)&pw_hi[vrow * 1024 + kb + c8];
            }
        } else {
            #pragma unroll
            for (int p = 0; p < 4; p++) {
                int idx = p * 256 + t;
                int r = idx >> 3, c8 = (idx & 7) * 8;
                long vrow = v0 + r; if (vrow >= VV) vrow = VV - 1;
                const float* src = &pw_f32[vrow * 1024 + kb + c8];
                const float4 f0 = *(const float4*)&src[0];
                const float4 f1 = *(const float4*)&src[4];
                s8v h;
                h[0] = f2bf(f0.x); h[1] = f2bf(f0.y); h[2] = f2bf(f0.z); h[3] = f2bf(f0.w);
                h[4] = f2bf(f1.x); h[5] = f2bf(f1.y); h[6] = f2bf(f1.z); h[7] = f2bf(f1.w);
                *(s8v*)&Ah[r][c8] = h;
            }
        }
        #pragma unroll
        for (int p = 0; p < 2; p++) {
            int idx = p * 256 + t;
            int r = idx >> 3, c8 = (idx & 7) * 8;
            *(s8v*)&Bh[r][c8] = *(const s8v*)&cat_hi[r * 1024 + kb + c8];
        }
        __syncthreads();
        #pragma unroll
        for (int kc = 0; kc < 64; kc += 32) {
            const int ko = kc + (lane >> 4) * 8;
            const int fr = lane & 15;
            s8v ah0 = *(s8v*)&Ah[wave * 32 + fr][ko];
            s8v ah1 = *(s8v*)&Ah[wave * 32 + 16 + fr][ko];
            s8v bh[4];
            #pragma unroll
            for (int fb = 0; fb < 4; fb++) bh[fb] = *(s8v*)&Bh[fb * 16 + fr][ko];
            #pragma unroll
            for (int fb = 0; fb < 4; fb++) {
                acc[0][fb] = __builtin_amdgcn_mfma_f32_16x16x32_bf16(ah0, bh[fb], acc[0][fb], 0, 0, 0);
                acc[1][fb] = __builtin_amdgcn_mfma_f32_16x16x32_bf16(ah1, bh[fb], acc[1][fb], 0, 0, 0);
            }
        }
        __syncthreads();
    }

    const int col = lane & 15;
    #pragma unroll
    for (int fv = 0; fv < 2; fv++) {
        int rloc = wave * 32 + fv * 16 + (lane >> 4) * 4;
        int vbase = v0 + rloc;
        float pbv[4];
        #pragma unroll
        for (int i = 0; i < 4; i++) pbv[i] = (vbase + i < VV) ? pb[vbase + i] : 0.f;
        #pragma unroll
        for (int fb = 0; fb < 4; fb++) {
            int b = fb * 16 + col;
            float o[4];
            #pragma unroll
            for (int i = 0; i < 4; i++) o[i] = acc[fv][fb][i] + pbv[i];
            if (vbase + 3 < VV) {
                float4 st; st.x = o[0]; st.y = o[1]; st.z = o[2]; st.w = o[3];
                *(float4*)&logits[(long)b * VV + vbase] = st;
            } else {
                for (int i = 0; i < 4; i++)
                    if (vbase + i < VV) logits[(long)b * VV + vbase + i] = o[i];
            }
            #pragma unroll
            for (int i = 0; i < 4; i++)
                LT[b][rloc + i] = (vbase + i < VV) ? o[i] : -INFINITY;
        }
    }
    __syncthreads();

    {
        int b = t & 63, q = t >> 6;
        float m = -INFINITY, s = 0.f;
        for (int r = q * 32; r < q * 32 + 32; r++) {
            float v = LT[b][r];
            if (v == -INFINITY) continue;
            if (v > m) { s = s * expf(m - v) + 1.f; m = v; }
            else s += expf(v - m);
        }
        sm4[q][b] = m; ss4[q][b] = s;
    }
    __syncthreads();
    if (t < 64) {
        int b = t;
        float M = sm4[0][b], S = ss4[0][b];
        #pragma unroll
        for (int q = 1; q < 4; q++) {
            float m2 = sm4[q][b], s2 = ss4[q][b];
            if (m2 > M) { S = S * expf(M - m2) + s2; M = m2; }
            else if (m2 != -INFINITY) S += s2 * expf(m2 - M);
        }
        pm[blockIdx.x * 64 + b] = M;
        ps[blockIdx.x * 64 + b] = S;
    }

    // ---- normalize previous step's logits (proven fold) ----
    if (prev_logits) {
        const long total4 = (long)BB * VV / 4;
        for (long i4 = (long)blockIdx.x * 256 + t; i4 < total4; i4 += (long)NPB * 256) {
            long i = i4 * 4;
            float l = lse_prev[(int)(i / VV)];
            float4 x = *(float4*)&prev_logits[i];
            x.x -= l; x.y -= l; x.z -= l; x.w -= l;
            *(float4*)&prev_logits[i] = x;
        }
    }
}

// ---------- parallel per-b lse + candidate gather + exact fp32 refine (proven) ----------
__global__ __launch_bounds__(256) void reduce_par_kernel(
    const float* __restrict__ logits,   // [b][V] hi-only, this step
    const float* __restrict__ pm, const float* __restrict__ ps,
    const float* __restrict__ pw_f32, const float* __restrict__ pb,
    const float* __restrict__ cat_f32,
    int* __restrict__ tok, float* __restrict__ pred_out, float* __restrict__ lse_out)
{
    int b = blockIdx.x, t = threadIdx.x;
    int lane = t & 63, wave = t >> 6;
    __shared__ float red[256], red2[256];
    __shared__ float cf[2 * HH];
    __shared__ int   qlist[32];
    __shared__ int   vlist[32];
    __shared__ float ws4[4];
    __shared__ float bestv;
    __shared__ int   besti, qcnt, vcnt;

    for (int k = t; k < 2 * HH; k += 256) cf[k] = cat_f32[b * 2 * HH + k];
    if (t == 0) { qcnt = 0; vcnt = 0; bestv = -INFINITY; besti = 0; }

    float pmv = -INFINITY, psv = 0.f;
    if (t < NPB) { pmv = pm[t * 64 + b]; psv = ps[t * 64 + b]; }
    red[t] = pmv; red2[t] = psv;
    __syncthreads();
    for (int o = 128; o; o >>= 1) {
        if (t < o) {
            float m1 = red[t],     s1 = red2[t];
            float m2 = red[t + o], s2 = red2[t + o];
            if (m2 > m1) { red[t] = m2; red2[t] = s2 + s1 * expf(m1 - m2); }
            else if (m2 != -INFINITY) red2[t] = s1 + s2 * expf(m2 - m1);
        }
        __syncthreads();
    }
    float gm  = red[0];
    float lse = gm + logf(red2[0]);
    float thr = gm - TAU;

    if (t < NPB && pmv >= thr) {
        int p = atomicAdd(&qcnt, 1);
        if (p < 32) qlist[p] = t;
    }
    __syncthreads();
    int qn = qcnt; if (qn > 32) qn = 32;

    for (int qi = 0; qi < qn; qi++) {
        int ib = qlist[qi];
        if (t < 128) {
            int v = ib * 128 + t;
            if (v < VV) {
                float lv = logits[(long)b * VV + v];
                if (lv >= thr) {
                    int p = atomicAdd(&vcnt, 1);
                    if (p < 32) vlist[p] = v;
                }
            }
        }
    }
    __syncthreads();
    int nv = vcnt; if (nv > 32) nv = 32;

    for (int c = 0; c < nv; c++) {
        int vr = vlist[c];
        float p = 0.f;
        for (int k = t; k < 2 * HH; k += 256)
            p += pw_f32[(long)vr * 2 * HH + k] * cf[k];
        for (int o = 32; o; o >>= 1) p += __shfl_down(p, o);
        if (lane == 0) ws4[wave] = p;
        __syncthreads();
        if (t == 0) {
            float val = ws4[0] + ws4[1] + ws4[2] + ws4[3] + pb[vr];
            if (val > bestv || (val == bestv && vr < besti)) { bestv = val; besti = vr; }
        }
        __syncthreads();
    }
    if (t == 0) {
        tok[b] = besti;
        pred_out[b] = (float)besti;
        lse_out[b] = lse;
    }
}

// ---------- normalize last step's logits ----------
__global__ __launch_bounds__(256) void norm_last_kernel(
    float* __restrict__ prev_logits, const float* __restrict__ lse_prev)
{
    const long total4 = (long)BB * VV / 4;
    for (long i4 = (long)blockIdx.x * 256 + threadIdx.x; i4 < total4;
         i4 += (long)gridDim.x * 256) {
        long i = i4 * 4;
        float l = lse_prev[(int)(i / VV)];
        float4 x = *(float4*)&prev_logits[i];
        x.x -= l; x.y -= l; x.z -= l; x.w -= l;
        *(float4*)&prev_logits[i] = x;
    }
}

extern "C" void kernel_launch(void* const* d_in, const int* in_sizes, int n_in,
                              void* d_out, int out_size, void* d_ws, size_t ws_size,
                              hipStream_t stream) {
    const int*   input     = (const int*)  d_in[0];
    const float* enc_embed = (const float*)d_in[1];
    const float* enc_wih   = (const float*)d_in[2];
    const float* enc_whh   = (const float*)d_in[3];
    const float* enc_bih   = (const float*)d_in[4];
    const float* enc_bhh   = (const float*)d_in[5];
    const float* dec_embed = (const float*)d_in[6];
    const float* dec_wih   = (const float*)d_in[7];
    const float* dec_whh   = (const float*)d_in[8];
    const float* dec_bih   = (const float*)d_in[9];
    const float* dec_bhh   = (const float*)d_in[10];
    const float* proj_w    = (const float*)d_in[11];
    const float* proj_b    = (const float*)d_in[12];

    float* out       = (float*)d_out;
    float* pred_out  = out;            // S*B
    float* dists_out = out + SS * BB;  // S*B*V

    float* ws = (float*)d_ws;
    long off = 0;
    float* enc_states = ws + off; off += (long)BB * SS * HH;
    float* gi_all     = ws + off; off += (long)SS * G3 * BB;
    float* hbuf       = ws + off; off += BB * HH;
    float* cat_f32    = ws + off; off += BB * 2 * HH;
    short* cat_hi     = (short*)(ws + off); off += BB * 2 * HH / 2;
    float* pm         = ws + off; off += NPB * 64;
    float* ps         = ws + off; off += NPB * 64;
    float* lse_arr    = ws + off; off += SS * BB;
    int*   tok        = (int*)(ws + off); off += BB;

    const long pw_elems = (long)VV * 2 * HH;  // 30,720,000
    bool use_split = ((long)ws_size >= (off + pw_elems / 2) * 4 + 1024);
    short* pw_hi = nullptr;
    if (use_split) {
        pw_hi = (short*)(ws + off);
        split_hi_kernel<<<2048, 256, 0, stream>>>(proj_w, pw_elems / 4, pw_hi);
    }

    // ---------------- encoder (proven chain; 256-block step kernels) ----------------
    enc_gi_all_kernel<<<dim3(G3 / 64, SS), 256, 0, stream>>>(input, enc_embed, enc_wih, gi_all);
    for (int s = 0; s < SS; s++) {
        const float* hprev = s ? enc_states + (long)(s - 1) * HH : nullptr;
        enc_step_kernel<<<HH / 2, 128, 0, stream>>>(
            gi_all + (long)s * G3 * BB, enc_whh, enc_bih, enc_bhh,
            hprev, s, enc_states);
    }

    // ---------------- decoder (proven chain + normalize fold; 256-block step kernels) ----------------
    for (int s = 0; s < SS; s++) {
        const float* hprev; long hstride;
        if (s == 0) { hprev = enc_states + (long)(SS - 1) * HH; hstride = (long)SS * HH; }
        else        { hprev = cat_f32;                          hstride = 2 * HH; }

        dec_step_kernel<<<HH / 2, 128, 0, stream>>>(tok, s, dec_embed,
                                                    dec_wih, dec_whh, dec_bih, dec_bhh,
                                                    hprev, hstride, hbuf);
        dec_attn_kernel<<<BB, 256, 0, stream>>>(hbuf, enc_states, cat_f32, cat_hi);

        float* logits = dists_out + (long)s * BB * VV;
        float* prev_logits = (s > 0) ? (dists_out + (long)(s - 1) * BB * VV) : nullptr;
        const float* lse_prev = (s > 0) ? (lse_arr + (s - 1) * BB) : nullptr;
        proj_hi_kernel<<<NPB, 256, 0, stream>>>(pw_hi, proj_w, cat_hi, proj_b, logits, pm, ps,
                                                prev_logits, lse_prev);
        reduce_par_kernel<<<BB, 256, 0, stream>>>(logits, pm, ps, proj_w, proj_b, cat_f32,
                                                  tok, pred_out + s * BB, lse_arr + s * BB);
    }

    norm_last_kernel<<<512, 256, 0, stream>>>(dists_out + (long)(SS - 1) * BB * VV,
                                              lse_arr + (SS - 1) * BB);
}

// Round 19
// 5216.242 us; speedup vs baseline: 1.0342x; 1.0342x over previous
//
#include <hip/hip_runtime.h>
#include <math.h>

#define BB 64
#define SS 48
#define EE 256
#define HH 512
#define VV 30000
#define G3 1536   // 3*H
#define NPB 235   // ceil(VV/128) proj blocks
#define TAU 0.04f

typedef __attribute__((ext_vector_type(8))) short s8v;
typedef __attribute__((ext_vector_type(4))) short s4v;
typedef __attribute__((ext_vector_type(4))) float f4v;

__device__ __forceinline__ float sigmoidf_(float x) { return 1.f / (1.f + expf(-x)); }

__device__ __forceinline__ short f2bf(float x) {
    union { float f; unsigned u; } v; v.f = x;
    unsigned r = v.u + 0x7fffu + ((v.u >> 16) & 1u);
    return (short)(r >> 16);
}

// ---------- split fp32 -> bf16 hi only (proven) ----------
__global__ __launch_bounds__(256) void split_hi_kernel(
    const float* __restrict__ src, long n4, short* __restrict__ hi)
{
    for (long i = (long)blockIdx.x * 256 + threadIdx.x; i < n4;
         i += (long)gridDim.x * 256) {
        const float4 x = *(const float4*)&src[i * 4];
        s4v h;
        h[0] = f2bf(x.x); h[1] = f2bf(x.y); h[2] = f2bf(x.z); h[3] = f2bf(x.w);
        *(s4v*)&hi[i * 4] = h;
    }
}

// ---------- encoder gi for ALL steps (proven) ----------
__global__ __launch_bounds__(256) void enc_gi_all_kernel(
    const int* __restrict__ input,
    const float* __restrict__ embed,
    const float* __restrict__ wih,
    float* __restrict__ gi_all)           // [S][G3][B]
{
    __shared__ float Wt[64][68];
    __shared__ float Xt[64][68];
    const int t  = threadIdx.x;
    const int tx = t & 15, ty = t >> 4;
    const int j0 = blockIdx.x * 64;
    const int s  = blockIdx.y;
    const int bb = t & 63, kq = t >> 6;
    const int wkk = (t & 15) * 4, wjj = t >> 4;

    const long xrow = (long)input[bb * SS + s] * EE;
    float* gi = gi_all + (long)s * G3 * BB;

    float acc[4][4];
    #pragma unroll
    for (int i = 0; i < 4; i++)
        #pragma unroll
        for (int j = 0; j < 4; j++) acc[i][j] = 0.f;

    for (int kb = 0; kb < EE; kb += 64) {
        #pragma unroll
        for (int r = 0; r < 4; r++) {
            int row = j0 + wjj + r * 16;
            const float4 w = *(const float4*)&wih[row * EE + kb + wkk];
            Wt[wkk + 0][wjj + r * 16] = w.x;
            Wt[wkk + 1][wjj + r * 16] = w.y;
            Wt[wkk + 2][wjj + r * 16] = w.z;
            Wt[wkk + 3][wjj + r * 16] = w.w;
        }
        {
            const float* src = embed + xrow + kb + kq * 16;
            #pragma unroll
            for (int q = 0; q < 4; q++) {
                const float4 x = *(const float4*)&src[q * 4];
                Xt[kq * 16 + q * 4 + 0][bb] = x.x;
                Xt[kq * 16 + q * 4 + 1][bb] = x.y;
                Xt[kq * 16 + q * 4 + 2][bb] = x.z;
                Xt[kq * 16 + q * 4 + 3][bb] = x.w;
            }
        }
        __syncthreads();
        #pragma unroll 8
        for (int k = 0; k < 64; k++) {
            const float4 a = *(const float4*)&Wt[k][ty * 4];
            const float4 x = *(const float4*)&Xt[k][tx * 4];
            acc[0][0] += a.x * x.x; acc[0][1] += a.x * x.y; acc[0][2] += a.x * x.z; acc[0][3] += a.x * x.w;
            acc[1][0] += a.y * x.x; acc[1][1] += a.y * x.y; acc[1][2] += a.y * x.z; acc[1][3] += a.y * x.w;
            acc[2][0] += a.z * x.x; acc[2][1] += a.z * x.y; acc[2][2] += a.z * x.z; acc[2][3] += a.z * x.w;
            acc[3][0] += a.w * x.x; acc[3][1] += a.w * x.y; acc[3][2] += a.w * x.z; acc[3][3] += a.w * x.w;
        }
        __syncthreads();
    }
    #pragma unroll
    for (int i = 0; i < 4; i++) {
        float4 o; o.x = acc[i][0]; o.y = acc[i][1]; o.z = acc[i][2]; o.w = acc[i][3];
        *(float4*)&gi[(j0 + ty * 4 + i) * BB + tx * 4] = o;
    }
}

// ---------- fused encoder step: 128 blocks x 4 hidden (R17-proven optimum) ----------
__global__ __launch_bounds__(256) void enc_step_kernel(
    const float* __restrict__ gi_s,
    const float* __restrict__ whh,
    const float* __restrict__ bih, const float* __restrict__ bhh,
    const float* __restrict__ hprev, int s,
    float* __restrict__ enc_states)
{
    __shared__ __attribute__((aligned(16))) float Wt[64][13];  // [k][g*4+r]
    __shared__ __attribute__((aligned(16))) float Xt[64][68];
    const int t = threadIdx.x;
    const int tx = t & 63, ty = t >> 6;          // b, hidden offset (0..3)
    const int bb = t & 63, kq = t >> 6;          // X staging
    const int wlr = t >> 5, wc2 = (t & 31) * 2;  // W staging (t<128: wlr 0..3)
    const int h0 = blockIdx.x * 4;

    float accr = 0.f, accz = 0.f, acchn = 0.f;

    if (hprev) {
        const float* xr = hprev + (long)bb * (SS * HH);
        for (int kb = 0; kb < HH; kb += 64) {
            if (t < 128) {
                #pragma unroll
                for (int g = 0; g < 3; g++) {
                    const float2 w = *(const float2*)&whh[(long)(g * HH + h0 + wlr) * HH + kb + wc2];
                    Wt[wc2 + 0][g * 4 + wlr] = w.x;
                    Wt[wc2 + 1][g * 4 + wlr] = w.y;
                }
            }
            {
                const float* src = xr + kb + kq * 16;
                #pragma unroll
                for (int q = 0; q < 4; q++) {
                    const float4 x = *(const float4*)&src[q * 4];
                    Xt[kq * 16 + q * 4 + 0][bb] = x.x;
                    Xt[kq * 16 + q * 4 + 1][bb] = x.y;
                    Xt[kq * 16 + q * 4 + 2][bb] = x.z;
                    Xt[kq * 16 + q * 4 + 3][bb] = x.w;
                }
            }
            __syncthreads();
            #pragma unroll 8
            for (int k = 0; k < 64; k++) {
                float x = Xt[k][tx];
                accr  += Wt[k][ty] * x;
                accz  += Wt[k][4 + ty] * x;
                acchn += Wt[k][8 + ty] * x;
            }
            __syncthreads();
        }
    }

    const int j = h0 + ty;
    const int b = tx;
    float r = sigmoidf_(gi_s[(long)j * BB + b] + accr + bih[j] + bhh[j]);
    float z = sigmoidf_(gi_s[(long)(HH + j) * BB + b] + accz + bih[HH + j] + bhh[HH + j]);
    float n = tanhf(gi_s[(long)(2 * HH + j) * BB + b] + bih[2 * HH + j] + r * (acchn + bhh[2 * HH + j]));
    float hp = hprev ? hprev[(long)b * (SS * HH) + j] : 0.f;
    enc_states[((long)b * SS + s) * HH + j] = (1.f - z) * n + z * hp;
}

// ---------- fused decoder step: 128 blocks x 4 hidden (R17-proven optimum) ----------
__global__ __launch_bounds__(256) void dec_step_kernel(
    const int* __restrict__ tok, int s,
    const float* __restrict__ embed,
    const float* __restrict__ wih, const float* __restrict__ whh,
    const float* __restrict__ bih, const float* __restrict__ bhh,
    const float* __restrict__ hprev, long hstride,
    float* __restrict__ hbuf)                       // [B][H]
{
    __shared__ __attribute__((aligned(16))) float Wt[64][13];
    __shared__ __attribute__((aligned(16))) float Xt[64][68];
    const int t = threadIdx.x;
    const int tx = t & 63, ty = t >> 6;
    const int bb = t & 63, kq = t >> 6;
    const int wlr = t >> 5, wc2 = (t & 31) * 2;
    const int h0 = blockIdx.x * 4;

    float accr = 0.f, accz = 0.f, accin = 0.f, acchn = 0.f;

    // ---- phase A: wih (K=EE), X = embed[token] ----
    {
        const int tk = (s == 0) ? 0 : tok[bb];
        const float* xr = embed + (long)tk * EE;
        for (int kb = 0; kb < EE; kb += 64) {
            if (t < 128) {
                #pragma unroll
                for (int g = 0; g < 3; g++) {
                    const float2 w = *(const float2*)&wih[(long)(g * HH + h0 + wlr) * EE + kb + wc2];
                    Wt[wc2 + 0][g * 4 + wlr] = w.x;
                    Wt[wc2 + 1][g * 4 + wlr] = w.y;
                }
            }
            {
                const float* src = xr + kb + kq * 16;
                #pragma unroll
                for (int q = 0; q < 4; q++) {
                    const float4 x = *(const float4*)&src[q * 4];
                    Xt[kq * 16 + q * 4 + 0][bb] = x.x;
                    Xt[kq * 16 + q * 4 + 1][bb] = x.y;
                    Xt[kq * 16 + q * 4 + 2][bb] = x.z;
                    Xt[kq * 16 + q * 4 + 3][bb] = x.w;
                }
            }
            __syncthreads();
            #pragma unroll 8
            for (int k = 0; k < 64; k++) {
                float x = Xt[k][tx];
                accr  += Wt[k][ty] * x;
                accz  += Wt[k][4 + ty] * x;
                accin += Wt[k][8 + ty] * x;
            }
            __syncthreads();
        }
    }
    // ---- phase B: whh (K=HH), X = hprev ----
    {
        const float* xr = hprev + (long)bb * hstride;
        for (int kb = 0; kb < HH; kb += 64) {
            if (t < 128) {
                #pragma unroll
                for (int g = 0; g < 3; g++) {
                    const float2 w = *(const float2*)&whh[(long)(g * HH + h0 + wlr) * HH + kb + wc2];
                    Wt[wc2 + 0][g * 4 + wlr] = w.x;
                    Wt[wc2 + 1][g * 4 + wlr] = w.y;
                }
            }
            {
                const float* src = xr + kb + kq * 16;
                #pragma unroll
                for (int q = 0; q < 4; q++) {
                    const float4 x = *(const float4*)&src[q * 4];
                    Xt[kq * 16 + q * 4 + 0][bb] = x.x;
                    Xt[kq * 16 + q * 4 + 1][bb] = x.y;
                    Xt[kq * 16 + q * 4 + 2][bb] = x.z;
                    Xt[kq * 16 + q * 4 + 3][bb] = x.w;
                }
            }
            __syncthreads();
            #pragma unroll 8
            for (int k = 0; k < 64; k++) {
                float x = Xt[k][tx];
                accr  += Wt[k][ty] * x;
                accz  += Wt[k][4 + ty] * x;
                acchn += Wt[k][8 + ty] * x;
            }
            __syncthreads();
        }
    }

    const int j = h0 + ty;
    const int b = tx;
    float r = sigmoidf_(accr + bih[j] + bhh[j]);
    float z = sigmoidf_(accz + bih[HH + j] + bhh[HH + j]);
    float n = tanhf(accin + bih[2 * HH + j] + r * (acchn + bhh[2 * HH + j]));
    float hp = hprev[(long)b * hstride + j];
    hbuf[b * HH + j] = (1.f - z) * n + z * hp;
}

// ---------- decoder attention (proven) ----------
__global__ __launch_bounds__(256) void dec_attn_kernel(
    const float* __restrict__ hbuf,         // [b][H]
    const float* __restrict__ enc_states,   // [b][s][h]
    float* __restrict__ cat_f32,            // [b][2H]
    short* __restrict__ cat_hi)             // [b][2H] bf16
{
    int b = blockIdx.x, t = threadIdx.x;
    __shared__ float hs[HH];
    __shared__ float ctxs[HH];
    __shared__ float sc[SS];

    for (int j = t; j < HH; j += 256) hs[j] = hbuf[b * HH + j];
    __syncthreads();

    int wave = t >> 6, lane = t & 63;
    for (int sp = wave; sp < SS; sp += 4) {
        const float* es = enc_states + ((long)b * SS + sp) * HH;
        float p = 0.f;
        for (int k = lane; k < HH; k += 64) p += es[k] * hs[k];
        for (int o = 32; o; o >>= 1) p += __shfl_down(p, o);
        if (lane == 0) sc[sp] = p;
    }
    __syncthreads();
    if (t == 0) {
        float m = sc[0];
        for (int i = 1; i < SS; i++) m = fmaxf(m, sc[i]);
        float sum = 0.f;
        for (int i = 0; i < SS; i++) { float e = expf(sc[i] - m); sc[i] = e; sum += e; }
        float inv = 1.f / sum;
        for (int i = 0; i < SS; i++) sc[i] *= inv;
    }
    __syncthreads();
    for (int j = t; j < HH; j += 256) {
        float c = 0.f;
        for (int sp = 0; sp < SS; sp++) c += sc[sp] * enc_states[((long)b * SS + sp) * HH + j];
        ctxs[j] = c;
    }
    __syncthreads();
    for (int k = t; k < 2 * HH; k += 256) {
        float val = (k < HH) ? hs[k] : ctxs[k - HH];
        cat_f32[b * 2 * HH + k] = val;
        cat_hi[b * 2 * HH + k] = f2bf(val);
    }
}

// ---------- projection hi-only MFMA + per-block stats + normalize prev (proven fold) ----------
__global__ __launch_bounds__(256) void proj_hi_kernel(
    const short* __restrict__ pw_hi,     // may be null
    const float* __restrict__ pw_f32,
    const short* __restrict__ cat_hi,    // [B][2H]
    const float* __restrict__ pb,
    float* __restrict__ logits,          // [b][V]
    float* __restrict__ pm, float* __restrict__ ps,   // [NPB][64]
    float* __restrict__ prev_logits,     // may be null
    const float* __restrict__ lse_prev)
{
    __shared__ __attribute__((aligned(16))) char smem_raw[64 * 129 * 4];  // 33024 B
    short (*Ah)[72] = (short(*)[72])smem_raw;
    short (*Bh)[72] = (short(*)[72])(smem_raw + 128 * 72 * 2);
    float (*LT)[129] = (float(*)[129])smem_raw;
    __shared__ float sm4[4][64];
    __shared__ float ss4[4][64];

    const int t = threadIdx.x;
    const int lane = t & 63, wave = t >> 6;
    const int v0 = blockIdx.x * 128;

    f4v acc[2][4];
    #pragma unroll
    for (int i = 0; i < 2; i++)
        #pragma unroll
        for (int j = 0; j < 4; j++) acc[i][j] = (f4v){0.f, 0.f, 0.f, 0.f};

    for (int ks = 0; ks < 16; ks++) {
        const int kb = ks * 64;
        if (pw_hi) {
            #pragma unroll
            for (int p = 0; p < 4; p++) {
                int idx = p * 256 + t;
                int r = idx >> 3, c8 = (idx & 7) * 8;
                long vrow = v0 + r; if (vrow >= VV) vrow = VV - 1;
                *(s8v*)&Ah[r][c8] = *(const s8v*)&pw_hi[vrow * 1024 + kb + c8];
            }
        } else {
            #pragma unroll
            for (int p = 0; p < 4; p++) {
                int idx = p * 256 + t;
                int r = idx >> 3, c8 = (idx & 7) * 8;
                long vrow = v0 + r; if (vrow >= VV) vrow = VV - 1;
                const float* src = &pw_f32[vrow * 1024 + kb + c8];
                const float4 f0 = *(const float4*)&src[0];
                const float4 f1 = *(const float4*)&src[4];
                s8v h;
                h[0] = f2bf(f0.x); h[1] = f2bf(f0.y); h[2] = f2bf(f0.z); h[3] = f2bf(f0.w);
                h[4] = f2bf(f1.x); h[5] = f2bf(f1.y); h[6] = f2bf(f1.z); h[7] = f2bf(f1.w);
                *(s8v*)&Ah[r][c8] = h;
            }
        }
        #pragma unroll
        for (int p = 0; p < 2; p++) {
            int idx = p * 256 + t;
            int r = idx >> 3, c8 = (idx & 7) * 8;
            *(s8v*)&Bh[r][c8] = *(const s8v*)&cat_hi[r * 1024 + kb + c8];
        }
        __syncthreads();
        #pragma unroll
        for (int kc = 0; kc < 64; kc += 32) {
            const int ko = kc + (lane >> 4) * 8;
            const int fr = lane & 15;
            s8v ah0 = *(s8v*)&Ah[wave * 32 + fr][ko];
            s8v ah1 = *(s8v*)&Ah[wave * 32 + 16 + fr][ko];
            s8v bh[4];
            #pragma unroll
            for (int fb = 0; fb < 4; fb++) bh[fb] = *(s8v*)&Bh[fb * 16 + fr][ko];
            #pragma unroll
            for (int fb = 0; fb < 4; fb++) {
                acc[0][fb] = __builtin_amdgcn_mfma_f32_16x16x32_bf16(ah0, bh[fb], acc[0][fb], 0, 0, 0);
                acc[1][fb] = __builtin_amdgcn_mfma_f32_16x16x32_bf16(ah1, bh[fb], acc[1][fb], 0, 0, 0);
            }
        }
        __syncthreads();
    }

    const int col = lane & 15;
    #pragma unroll
    for (int fv = 0; fv < 2; fv++) {
        int rloc = wave * 32 + fv * 16 + (lane >> 4) * 4;
        int vbase = v0 + rloc;
        float pbv[4];
        #pragma unroll
        for (int i = 0; i < 4; i++) pbv[i] = (vbase + i < VV) ? pb[vbase + i] : 0.f;
        #pragma unroll
        for (int fb = 0; fb < 4; fb++) {
            int b = fb * 16 + col;
            float o[4];
            #pragma unroll
            for (int i = 0; i < 4; i++) o[i] = acc[fv][fb][i] + pbv[i];
            if (vbase + 3 < VV) {
                float4 st; st.x = o[0]; st.y = o[1]; st.z = o[2]; st.w = o[3];
                *(float4*)&logits[(long)b * VV + vbase] = st;
            } else {
                for (int i = 0; i < 4; i++)
                    if (vbase + i < VV) logits[(long)b * VV + vbase + i] = o[i];
            }
            #pragma unroll
            for (int i = 0; i < 4; i++)
                LT[b][rloc + i] = (vbase + i < VV) ? o[i] : -INFINITY;
        }
    }
    __syncthreads();

    {
        int b = t & 63, q = t >> 6;
        float m = -INFINITY, s = 0.f;
        for (int r = q * 32; r < q * 32 + 32; r++) {
            float v = LT[b][r];
            if (v == -INFINITY) continue;
            if (v > m) { s = s * expf(m - v) + 1.f; m = v; }
            else s += expf(v - m);
        }
        sm4[q][b] = m; ss4[q][b] = s;
    }
    __syncthreads();
    if (t < 64) {
        int b = t;
        float M = sm4[0][b], S = ss4[0][b];
        #pragma unroll
        for (int q = 1; q < 4; q++) {
            float m2 = sm4[q][b], s2 = ss4[q][b];
            if (m2 > M) { S = S * expf(M - m2) + s2; M = m2; }
            else if (m2 != -INFINITY) S += s2 * expf(m2 - M);
        }
        pm[blockIdx.x * 64 + b] = M;
        ps[blockIdx.x * 64 + b] = S;
    }

    // ---- normalize previous step's logits (proven fold) ----
    if (prev_logits) {
        const long total4 = (long)BB * VV / 4;
        for (long i4 = (long)blockIdx.x * 256 + t; i4 < total4; i4 += (long)NPB * 256) {
            long i = i4 * 4;
            float l = lse_prev[(int)(i / VV)];
            float4 x = *(float4*)&prev_logits[i];
            x.x -= l; x.y -= l; x.z -= l; x.w -= l;
            *(float4*)&prev_logits[i] = x;
        }
    }
}

// ---------- parallel per-b lse + candidate gather + exact fp32 refine (proven) ----------
__global__ __launch_bounds__(256) void reduce_par_kernel(
    const float* __restrict__ logits,   // [b][V] hi-only, this step
    const float* __restrict__ pm, const float* __restrict__ ps,
    const float* __restrict__ pw_f32, const float* __restrict__ pb,
    const float* __restrict__ cat_f32,
    int* __restrict__ tok, float* __restrict__ pred_out, float* __restrict__ lse_out)
{
    int b = blockIdx.x, t = threadIdx.x;
    int lane = t & 63, wave = t >> 6;
    __shared__ float red[256], red2[256];
    __shared__ float cf[2 * HH];
    __shared__ int   qlist[32];
    __shared__ int   vlist[32];
    __shared__ float ws4[4];
    __shared__ float bestv;
    __shared__ int   besti, qcnt, vcnt;

    for (int k = t; k < 2 * HH; k += 256) cf[k] = cat_f32[b * 2 * HH + k];
    if (t == 0) { qcnt = 0; vcnt = 0; bestv = -INFINITY; besti = 0; }

    float pmv = -INFINITY, psv = 0.f;
    if (t < NPB) { pmv = pm[t * 64 + b]; psv = ps[t * 64 + b]; }
    red[t] = pmv; red2[t] = psv;
    __syncthreads();
    for (int o = 128; o; o >>= 1) {
        if (t < o) {
            float m1 = red[t],     s1 = red2[t];
            float m2 = red[t + o], s2 = red2[t + o];
            if (m2 > m1) { red[t] = m2; red2[t] = s2 + s1 * expf(m1 - m2); }
            else if (m2 != -INFINITY) red2[t] = s1 + s2 * expf(m2 - m1);
        }
        __syncthreads();
    }
    float gm  = red[0];
    float lse = gm + logf(red2[0]);
    float thr = gm - TAU;

    if (t < NPB && pmv >= thr) {
        int p = atomicAdd(&qcnt, 1);
        if (p < 32) qlist[p] = t;
    }
    __syncthreads();
    int qn = qcnt; if (qn > 32) qn = 32;

    for (int qi = 0; qi < qn; qi++) {
        int ib = qlist[qi];
        if (t < 128) {
            int v = ib * 128 + t;
            if (v < VV) {
                float lv = logits[(long)b * VV + v];
                if (lv >= thr) {
                    int p = atomicAdd(&vcnt, 1);
                    if (p < 32) vlist[p] = v;
                }
            }
        }
    }
    __syncthreads();
    int nv = vcnt; if (nv > 32) nv = 32;

    for (int c = 0; c < nv; c++) {
        int vr = vlist[c];
        float p = 0.f;
        for (int k = t; k < 2 * HH; k += 256)
            p += pw_f32[(long)vr * 2 * HH + k] * cf[k];
        for (int o = 32; o; o >>= 1) p += __shfl_down(p, o);
        if (lane == 0) ws4[wave] = p;
        __syncthreads();
        if (t == 0) {
            float val = ws4[0] + ws4[1] + ws4[2] + ws4[3] + pb[vr];
            if (val > bestv || (val == bestv && vr < besti)) { bestv = val; besti = vr; }
        }
        __syncthreads();
    }
    if (t == 0) {
        tok[b] = besti;
        pred_out[b] = (float)besti;
        lse_out[b] = lse;
    }
}

// ---------- normalize last step's logits ----------
__global__ __launch_bounds__(256) void norm_last_kernel(
    float* __restrict__ prev_logits, const float* __restrict__ lse_prev)
{
    const long total4 = (long)BB * VV / 4;
    for (long i4 = (long)blockIdx.x * 256 + threadIdx.x; i4 < total4;
         i4 += (long)gridDim.x * 256) {
        long i = i4 * 4;
        float l = lse_prev[(int)(i / VV)];
        float4 x = *(float4*)&prev_logits[i];
        x.x -= l; x.y -= l; x.z -= l; x.w -= l;
        *(float4*)&prev_logits[i] = x;
    }
}

extern "C" void kernel_launch(void* const* d_in, const int* in_sizes, int n_in,
                              void* d_out, int out_size, void* d_ws, size_t ws_size,
                              hipStream_t stream) {
    const int*   input     = (const int*)  d_in[0];
    const float* enc_embed = (const float*)d_in[1];
    const float* enc_wih   = (const float*)d_in[2];
    const float* enc_whh   = (const float*)d_in[3];
    const float* enc_bih   = (const float*)d_in[4];
    const float* enc_bhh   = (const float*)d_in[5];
    const float* dec_embed = (const float*)d_in[6];
    const float* dec_wih   = (const float*)d_in[7];
    const float* dec_whh   = (const float*)d_in[8];
    const float* dec_bih   = (const float*)d_in[9];
    const float* dec_bhh   = (const float*)d_in[10];
    const float* proj_w    = (const float*)d_in[11];
    const float* proj_b    = (const float*)d_in[12];

    float* out       = (float*)d_out;
    float* pred_out  = out;            // S*B
    float* dists_out = out + SS * BB;  // S*B*V

    float* ws = (float*)d_ws;
    long off = 0;
    float* enc_states = ws + off; off += (long)BB * SS * HH;
    float* gi_all     = ws + off; off += (long)SS * G3 * BB;
    float* hbuf       = ws + off; off += BB * HH;
    float* cat_f32    = ws + off; off += BB * 2 * HH;
    short* cat_hi     = (short*)(ws + off); off += BB * 2 * HH / 2;
    float* pm         = ws + off; off += NPB * 64;
    float* ps         = ws + off; off += NPB * 64;
    float* lse_arr    = ws + off; off += SS * BB;
    int*   tok        = (int*)(ws + off); off += BB;

    const long pw_elems = (long)VV * 2 * HH;  // 30,720,000
    bool use_split = ((long)ws_size >= (off + pw_elems / 2) * 4 + 1024);
    short* pw_hi = nullptr;
    if (use_split) {
        pw_hi = (short*)(ws + off);
        split_hi_kernel<<<2048, 256, 0, stream>>>(proj_w, pw_elems / 4, pw_hi);
    }

    // ---------------- encoder (proven chain; 128-block step kernels) ----------------
    enc_gi_all_kernel<<<dim3(G3 / 64, SS), 256, 0, stream>>>(input, enc_embed, enc_wih, gi_all);
    for (int s = 0; s < SS; s++) {
        const float* hprev = s ? enc_states + (long)(s - 1) * HH : nullptr;
        enc_step_kernel<<<HH / 4, 256, 0, stream>>>(
            gi_all + (long)s * G3 * BB, enc_whh, enc_bih, enc_bhh,
            hprev, s, enc_states);
    }

    // ---------------- decoder (proven chain + normalize fold; 128-block step kernels) ----------------
    for (int s = 0; s < SS; s++) {
        const float* hprev; long hstride;
        if (s == 0) { hprev = enc_states + (long)(SS - 1) * HH; hstride = (long)SS * HH; }
        else        { hprev = cat_f32;                          hstride = 2 * HH; }

        dec_step_kernel<<<HH / 4, 256, 0, stream>>>(tok, s, dec_embed,
                                                    dec_wih, dec_whh, dec_bih, dec_bhh,
                                                    hprev, hstride, hbuf);
        dec_attn_kernel<<<BB, 256, 0, stream>>>(hbuf, enc_states, cat_f32, cat_hi);

        float* logits = dists_out + (long)s * BB * VV;
        float* prev_logits = (s > 0) ? (dists_out + (long)(s - 1) * BB * VV) : nullptr;
        const float* lse_prev = (s > 0) ? (lse_arr + (s - 1) * BB) : nullptr;
        proj_hi_kernel<<<NPB, 256, 0, stream>>>(pw_hi, proj_w, cat_hi, proj_b, logits, pm, ps,
                                                prev_logits, lse_prev);
        reduce_par_kernel<<<BB, 256, 0, stream>>>(logits, pm, ps, proj_w, proj_b, cat_f32,
                                                  tok, pred_out + s * BB, lse_arr + s * BB);
    }

    norm_last_kernel<<<512, 256, 0, stream>>>(dists_out + (long)(SS - 1) * BB * VV,
                                              lse_arr + (SS - 1) * BB);
}